// Round 14
// baseline (382.969 us; speedup 1.0000x reference)
//
#include <hip/hip_runtime.h>

typedef __bf16 bf16x8 __attribute__((ext_vector_type(8)));
typedef float f32x4 __attribute__((ext_vector_type(4)));

#define B_ 2
#define T_ 2048
#define D_ 1024
#define H_ 16

__device__ __forceinline__ ushort f2bf(float f) {
  union { float f; unsigned u; } v; v.f = f;
  unsigned u = v.u;
  return (ushort)((u + 0x7FFFu + ((u >> 16) & 1u)) >> 16);
}
__device__ __forceinline__ float b2f(ushort u) {
  union { unsigned u; float f; } v; v.u = ((unsigned)u) << 16;
  return v.f;
}

// async global->LDS, 16B per lane; LDS dest is wave-uniform base + lane*16
__device__ __forceinline__ void g2l16(const void* g, void* l) {
  __builtin_amdgcn_global_load_lds(
      (const __attribute__((address_space(1))) unsigned int*)g,
      (__attribute__((address_space(3))) unsigned int*)l, 16, 0, 0);
}

// ---------------- cast x -> bf16 ----------------
__global__ __launch_bounds__(256) void cvt_kernel(const float* __restrict__ in,
                                                  ushort* __restrict__ out) {
  int i = (blockIdx.x * 256 + threadIdx.x) * 4;
  float4 v = *(const float4*)(in + i);
  ushort4 o;
  o.x = f2bf(v.x); o.y = f2bf(v.y); o.z = f2bf(v.z); o.w = f2bf(v.w);
  *(ushort4*)(out + i) = o;
}

// ---------------- transpose + cast: in[R][C] f32 -> out[C][R] bf16 ----------------
__global__ void transpose_cvt(const float* __restrict__ in, ushort* __restrict__ out,
                              int R, int C) {
  __shared__ float tile[32][33];
  int bx = blockIdx.x * 32, by = blockIdx.y * 32;
  int tx = threadIdx.x, ty = threadIdx.y;  // block (32,8)
  for (int i = 0; i < 32; i += 8)
    tile[ty + i][tx] = in[(size_t)(by + ty + i) * C + (bx + tx)];
  __syncthreads();
  for (int i = 0; i < 32; i += 8)
    out[(size_t)(bx + ty + i) * R + (by + tx)] = f2bf(tile[tx][ty + i]);
}

// ---------------- bf16 GEMM (m97-style): C[M,N] = A[M,K] * BT[N,K]^T (+bias) ----------------
__global__ __launch_bounds__(256) void gemm_bf16(
    const ushort* __restrict__ A, const ushort* __restrict__ BT,
    float* __restrict__ C, const float* __restrict__ bias,
    int M, int N, int K) {
  __shared__ alignas(16) ushort As[2][4096];  // 128 rows x 32 cols
  __shared__ alignas(16) ushort Bs[2][4096];
  int tid = threadIdx.x;
  int wave = tid >> 6, lane = tid & 63;
  int l16 = lane & 15, lhi = lane >> 4;
  int m0 = blockIdx.y * 128, n0 = blockIdx.x * 128;
  int wr = (wave >> 1) * 64, wc = (wave & 1) * 64;
  int srow = lane >> 2, sch = lane & 3;  // staging: 4 lanes per 64B row

  f32x4 acc[4][4] = {};

  auto stage = [&](int kk, int buf) {
    for (int i = 0; i < 2; ++i) {
      int rg = i * 4 + wave;  // 0..7, 16 rows each
      const ushort* ga = A + (size_t)(m0 + rg * 16 + srow) * K + kk + sch * 8;
      const ushort* gb = BT + (size_t)(n0 + rg * 16 + srow) * K + kk + sch * 8;
      g2l16(ga, &As[buf][rg * 512]);
      g2l16(gb, &Bs[buf][rg * 512]);
    }
  };

  stage(0, 0);
  int buf = 0;
  for (int kk = 0; kk < K; kk += 32) {
    __syncthreads();
    if (kk + 32 < K) stage(kk + 32, buf ^ 1);
    const ushort* Asb = As[buf];
    const ushort* Bsb = Bs[buf];
    bf16x8 af[4], bfr[4];
    for (int f = 0; f < 4; ++f)
      af[f] = *(const bf16x8*)(Asb + (wr + f * 16 + l16) * 32 + lhi * 8);
    for (int f = 0; f < 4; ++f)
      bfr[f] = *(const bf16x8*)(Bsb + (wc + f * 16 + l16) * 32 + lhi * 8);
    for (int fm = 0; fm < 4; ++fm)
      for (int fn = 0; fn < 4; ++fn)
        acc[fm][fn] = __builtin_amdgcn_mfma_f32_16x16x32_bf16(af[fm], bfr[fn], acc[fm][fn], 0, 0, 0);
    buf ^= 1;
  }
  for (int fm = 0; fm < 4; ++fm)
    for (int fn = 0; fn < 4; ++fn)
      for (int r = 0; r < 4; ++r) {
        int row = m0 + wr + fm * 16 + lhi * 4 + r;
        int col = n0 + wc + fn * 16 + l16;
        float v = acc[fm][fn][r];
        if (bias) v += bias[col];
        C[(size_t)row * N + col] = v;
      }
}

// ---------------- build Qaug/Kaug/V from qkv ----------------
__global__ __launch_bounds__(256) void augment_kernel(
    const float* __restrict__ qkv,  // [B*T, 3072]
    ushort* __restrict__ Qaug, ushort* __restrict__ Kaug, ushort* __restrict__ Vb) {
  int row = blockIdx.x;  // b*T + t
  int b = row >> 11;
  int t = row & 2047;
  int tid = threadIdx.x;
  const float* src = qkv + (size_t)row * 3072;
  for (int i = 0; i < 4; ++i) {
    int idx = tid + i * 256;  // 0..1023
    int h = idx >> 6, d = idx & 63;
    size_t obase = ((size_t)(b * H_ + h) * T_ + t);
    float q = src[idx];
    float k = src[1024 + idx];
    float v = src[2048 + idx];
    Qaug[obase * 128 + d] = f2bf(q * 0.125f);
    Kaug[obase * 128 + d] = f2bf(k);
    Vb[obase * 64 + d] = f2bf(v);
  }
  for (int i = 0; i < 2; ++i) {
    int idx = tid + i * 256;  // 0..511
    int h = idx >> 5, mm = idx & 31;
    int gdim = h * 64 + 2 * mm;
    float w = __expf(-9.2103403719761836f * (float)gdim * (1.0f / 1024.0f));
    float ang = w * (float)t;
    float si, co;
    __sincosf(ang, &si, &co);
    float qs = src[h * 64 + 2 * mm], qc = src[h * 64 + 2 * mm + 1];
    size_t obase = ((size_t)(b * H_ + h) * T_ + t);
    Qaug[obase * 128 + 64 + 2 * mm]     = f2bf((qs * si + qc * co) * 0.125f);
    Qaug[obase * 128 + 64 + 2 * mm + 1] = f2bf((qc * si - qs * co) * 0.125f);
    Kaug[obase * 128 + 64 + 2 * mm]     = f2bf(co);
    Kaug[obase * 128 + 64 + 2 * mm + 1] = f2bf(si);
  }
}

// ---------------- transpose V: [BH, T, 64] -> [BH, 64, T] ----------------
__global__ __launch_bounds__(256) void transpose_v(const ushort* __restrict__ Vb,
                                                   ushort* __restrict__ Vt) {
  __shared__ ushort tile[64][72];
  int bh = blockIdx.y, t0 = blockIdx.x * 64;
  int tid = threadIdx.x;
  for (int i = 0; i < 2; ++i) {
    int e = tid + i * 256;           // 0..511
    int row = e >> 3, ch = e & 7;    // t-row, 8 dims
    *(int4*)(&tile[row][ch * 8]) =
        *(const int4*)(Vb + ((size_t)bh * T_ + t0 + row) * 64 + ch * 8);
  }
  __syncthreads();
  for (int i = 0; i < 2; ++i) {
    int e = tid + i * 256;           // 0..511
    int d = e >> 3, ch = e & 7;      // dim-row, 8 t's
    union { int4 v; ushort u[8]; } pk;
    for (int u = 0; u < 8; ++u) pk.u[u] = tile[ch * 8 + u][d];
    *(int4*)(Vt + ((size_t)bh * 64 + d) * T_ + t0 + ch * 8) = pk.v;
  }
}

// ---------------- fused attention: single sweep, unnormalized P~, deferred norm ----------------
__global__ __launch_bounds__(256) void attn_fused(
    const ushort* __restrict__ Qaug,  // [BH, T, 128]
    const ushort* __restrict__ Kaug,  // [BH, T, 128]
    const ushort* __restrict__ Vt,    // [BH, 64, T]
    ushort* __restrict__ Pb,          // [BH, T, T] bf16 (lower-tri tiles only)
    float* __restrict__ invlb,        // [BH*T]
    ushort* __restrict__ ctxb) {      // [B*T, 1024] bf16
  // XCD-aware bijective swizzle: each XCD gets 4 whole bh (K+V = 3 MB, L2-resident)
  int flat = blockIdx.y * 32 + blockIdx.x;
  int wg = (flat & 7) * 128 + (flat >> 3);
  int bh = wg >> 5;
  int qt = 31 - (wg & 31);  // biggest blocks first within chunk
  int tid = threadIdx.x;
  int wave = tid >> 6, lane = tid & 63;
  int l16 = lane & 15, lhi = lane >> 4;
  int qb = wave * 16;
  int e7 = l16 & 7;

  __shared__ alignas(16) ushort Ks[2][8192];  // [key 0..63][128], chunk16-XOR-swizzled
  __shared__ alignas(16) ushort Vs[2][4096];  // [dim 0..63][64 keys], chunk-XOR-swizzled
  __shared__ alignas(16) ushort Ps[4096];     // [qrow][64 keys], wave-private rows

  const ushort* Kbase = Kaug + (size_t)bh * T_ * 128;
  const ushort* Vbase = Vt + (size_t)bh * 64 * T_;

  auto stageK = [&](int kt, int buf) {
    for (int i = 0; i < 4; ++i) {
      int rg = i * 4 + wave;
      int key = rg * 4 + (lane >> 4);
      const ushort* g = Kbase + ((size_t)(kt * 64 + key)) * 128 + (((lane & 15) ^ (key & 7)) << 3);
      g2l16(g, &Ks[buf][rg * 512]);
    }
  };
  auto stageV = [&](int kt, int buf) {
    for (int i = 0; i < 2; ++i) {
      int rg = i * 4 + wave;
      int dim = rg * 8 + (lane >> 3);
      const ushort* g = Vbase + (size_t)dim * T_ + kt * 64 + (((lane & 7) ^ (dim & 7)) << 3);
      g2l16(g, &Vs[buf][rg * 512]);
    }
  };

  bf16x8 qf[4];
  {
    const ushort* Qg = Qaug + ((size_t)bh * T_ + qt * 64 + qb + l16) * 128;
    for (int ks = 0; ks < 4; ++ks)
      qf[ks] = *(const bf16x8*)(Qg + ks * 32 + lhi * 8);
  }

  stageK(0, 0);
  stageV(0, 0);
  asm volatile("s_waitcnt vmcnt(0)" ::: "memory");
  __builtin_amdgcn_s_barrier();
  f32x4 cacc[4] = {};
  float plsum[4] = {0.f, 0.f, 0.f, 0.f};

  for (int kt = 0; kt <= qt; ++kt) {
    int buf = kt & 1;
    if (kt < qt) { stageK(kt + 1, buf ^ 1); stageV(kt + 1, buf ^ 1); }
    __builtin_amdgcn_sched_barrier(0);
    // QK^T
    const ushort* Kb = Ks[buf];
    f32x4 s[4] = {};
    for (int ks = 0; ks < 4; ++ks)
      for (int fn = 0; fn < 4; ++fn) {
        bf16x8 bfr = *(const bf16x8*)(Kb + (fn * 16 + l16) * 128 + ((((ks << 2) | lhi) ^ e7) << 3));
        s[fn] = __builtin_amdgcn_mfma_f32_16x16x32_bf16(qf[ks], bfr, s[fn], 0, 0, 0);
      }
    if (kt == qt) {
      for (int fn = 0; fn < 4; ++fn)
        for (int r = 0; r < 4; ++r)
          if (fn * 16 + l16 > qb + lhi * 4 + r) s[fn][r] = -1e30f;
    }
    // exp (unnormalized) -> Ps + plsum
    for (int fn = 0; fn < 4; ++fn)
      for (int r = 0; r < 4; ++r) {
        int row_loc = qb + lhi * 4 + r;
        float p = __expf(s[fn][r]);
        plsum[r] += p;
        Ps[row_loc * 64 + (((fn * 2 + (l16 >> 3)) ^ (row_loc & 7)) << 3) + e7] = f2bf(p);
      }
    // P is wave-private: wave-local wait suffices
    asm volatile("s_waitcnt lgkmcnt(0)" ::: "memory");
    __builtin_amdgcn_sched_barrier(0);
    // PV
    const ushort* Vb2 = Vs[buf];
    for (int ks = 0; ks < 2; ++ks) {
      bf16x8 pa = *(const bf16x8*)(Ps + (qb + l16) * 64 + ((((ks << 2) | lhi) ^ e7) << 3));
      for (int fn = 0; fn < 4; ++fn) {
        bf16x8 vb = *(const bf16x8*)(Vb2 + (fn * 16 + l16) * 64 + ((((ks << 2) | lhi) ^ e7) << 3));
        cacc[fn] = __builtin_amdgcn_mfma_f32_16x16x32_bf16(pa, vb, cacc[fn], 0, 0, 0);
      }
    }
    // dump P~ tile (wave's 16 rows x 128B) as 2 fully-coalesced 1KB stores
    for (int pass = 0; pass < 2; ++pass) {
      int row_loc = qb + pass * 8 + (lane >> 3);
      int j = lane & 7;
      int4 u = *(const int4*)(Ps + row_loc * 64 + ((j ^ (row_loc & 7)) << 3));
      *(int4*)(Pb + ((size_t)bh * T_ + qt * 64 + row_loc) * T_ + kt * 64 + j * 8) = u;
    }
    if (kt < qt) {
      // drain the 6 staging loads; leave the 2 P~ stores in flight
      asm volatile("s_waitcnt vmcnt(2)" ::: "memory");
      __builtin_amdgcn_s_barrier();
    }
  }

  // finalize: row sums -> invl; normalize ctx
  float invl[4];
  for (int r = 0; r < 4; ++r) {
    float v = plsum[r];
    for (int dd = 1; dd < 16; dd <<= 1) v += __shfl_xor(v, dd);
    invl[r] = 1.f / v;
    if (l16 == 0)
      invlb[(size_t)bh * T_ + qt * 64 + qb + lhi * 4 + r] = invl[r];
  }

  int b = bh >> 4, h = bh & 15;
  for (int fn = 0; fn < 4; ++fn)
    for (int r = 0; r < 4; ++r) {
      int t = qt * 64 + qb + lhi * 4 + r;
      int col = h * 64 + fn * 16 + l16;
      ctxb[((size_t)(b * T_ + t)) * 1024 + col] = f2bf(cacc[fn][r] * invl[r]);
    }
}

// ---------------- streaming scale: score = b2f(P~) * invl, zero upper triangle ----------------
__global__ __launch_bounds__(256) void scale_kernel(
    const ushort* __restrict__ Pb, const float* __restrict__ invlb,
    float* __restrict__ score) {
  int wave = threadIdx.x >> 6, lane = threadIdx.x & 63;
  int row0 = blockIdx.x * 16 + wave * 4;
  for (int rr = 0; rr < 4; ++rr) {
    int row = row0 + rr;            // 0..65535 = bh*2048 + t
    int t = row & 2047;
    int L = ((t >> 6) + 1) << 6;    // valid cols (masked-in-tile P~ are exact 0)
    float inv = invlb[row];
    const ushort* src = Pb + (size_t)row * 2048;
    float* dst = score + (size_t)row * 2048;
    for (int c = lane * 8; c < 2048; c += 512) {
      f32x4 lo = {0.f, 0.f, 0.f, 0.f}, hi = {0.f, 0.f, 0.f, 0.f};
      if (c < L) {
        int4 u = *(const int4*)(src + c);
        const ushort* us = (const ushort*)&u;
        lo[0] = b2f(us[0]) * inv; lo[1] = b2f(us[1]) * inv;
        lo[2] = b2f(us[2]) * inv; lo[3] = b2f(us[3]) * inv;
        hi[0] = b2f(us[4]) * inv; hi[1] = b2f(us[5]) * inv;
        hi[2] = b2f(us[6]) * inv; hi[3] = b2f(us[7]) * inv;
      }
      *(f32x4*)(dst + c) = lo;
      *(f32x4*)(dst + c + 4) = hi;
    }
  }
}

extern "C" void kernel_launch(void* const* d_in, const int* in_sizes, int n_in,
                              void* d_out, int out_size, void* d_ws, size_t ws_size,
                              hipStream_t stream) {
  const float* x    = (const float*)d_in[0];
  const float* Wqkv = (const float*)d_in[2];
  const float* Wout = (const float*)d_in[3];
  const float* bout = (const float*)d_in[4];

  char* ws = (char*)d_ws;
  ushort* xb    = (ushort*)(ws + 0);           //  8 MB
  ushort* wqkvT = (ushort*)(ws + 8388608);     //  6 MB
  ushort* woutT = (ushort*)(ws + 14680064);    //  2 MB
  float*  qkv   = (float*) (ws + 16777216);    // 48 MB (dead after augment)
  ushort* Qaug  = (ushort*)(ws + 67108864);    // 16 MB
  ushort* Kaug  = (ushort*)(ws + 83886080);    // 16 MB
  ushort* Vb    = (ushort*)(ws + 100663296);   //  8 MB
  ushort* ctxb  = (ushort*)(ws + 109051904);   //  8 MB
  ushort* Vt    = (ushort*)(ws + 16777216);    //  8 MB, overlaps dead qkv
  float*  invlb = (float*) (ws + 25165824);    // 256 KB, after Vt in dead-qkv region
  ushort* Pb    = (ushort*)(ws + 134217728);   // 256 MB bf16 P~ scratch

  float* out   = (float*)d_out;
  float* score = out + (size_t)4194304;  // B*T*D floats, then [B,H,T,T]

  cvt_kernel<<<4096, 256, 0, stream>>>(x, xb);
  dim3 tb(32, 8);
  transpose_cvt<<<dim3(3072 / 32, 1024 / 32), tb, 0, stream>>>(Wqkv, wqkvT, 1024, 3072);
  transpose_cvt<<<dim3(1024 / 32, 1024 / 32), tb, 0, stream>>>(Wout, woutT, 1024, 1024);
  gemm_bf16<<<dim3(24, 32), 256, 0, stream>>>(xb, wqkvT, qkv, nullptr, 4096, 3072, 1024);
  augment_kernel<<<4096, 256, 0, stream>>>(qkv, Qaug, Kaug, Vb);
  transpose_v<<<dim3(32, 32), 256, 0, stream>>>(Vb, Vt);
  attn_fused<<<dim3(32, 32), 256, 0, stream>>>(Qaug, Kaug, Vt, Pb, invlb, ctxb);
  scale_kernel<<<4096, 256, 0, stream>>>(Pb, invlb, score);
  gemm_bf16<<<dim3(8, 32), 256, 0, stream>>>(ctxb, woutT, out, bout, 4096, 1024, 1024);
}

// Round 15
// 315.164 us; speedup vs baseline: 1.2151x; 1.2151x over previous
//
#include <hip/hip_runtime.h>

typedef __bf16 bf16x8 __attribute__((ext_vector_type(8)));
typedef float f32x4 __attribute__((ext_vector_type(4)));
typedef float f32x16 __attribute__((ext_vector_type(16)));

#define B_ 2
#define T_ 2048
#define D_ 1024
#define H_ 16

__device__ __forceinline__ ushort f2bf(float f) {
  union { float f; unsigned u; } v; v.f = f;
  unsigned u = v.u;
  return (ushort)((u + 0x7FFFu + ((u >> 16) & 1u)) >> 16);
}

// async global->LDS, 16B per lane; LDS dest is wave-uniform base + lane*16
__device__ __forceinline__ void g2l16(const void* g, void* l) {
  __builtin_amdgcn_global_load_lds(
      (const __attribute__((address_space(1))) unsigned int*)g,
      (__attribute__((address_space(3))) unsigned int*)l, 16, 0, 0);
}

// ---------------- cast x -> bf16 ----------------
__global__ __launch_bounds__(256) void cvt_kernel(const float* __restrict__ in,
                                                  ushort* __restrict__ out) {
  int i = (blockIdx.x * 256 + threadIdx.x) * 4;
  float4 v = *(const float4*)(in + i);
  ushort4 o;
  o.x = f2bf(v.x); o.y = f2bf(v.y); o.z = f2bf(v.z); o.w = f2bf(v.w);
  *(ushort4*)(out + i) = o;
}

// ---------------- transpose + cast: in[R][C] f32 -> out[C][R] bf16 ----------------
__global__ void transpose_cvt(const float* __restrict__ in, ushort* __restrict__ out,
                              int R, int C) {
  __shared__ float tile[32][33];
  int bx = blockIdx.x * 32, by = blockIdx.y * 32;
  int tx = threadIdx.x, ty = threadIdx.y;  // block (32,8)
  for (int i = 0; i < 32; i += 8)
    tile[ty + i][tx] = in[(size_t)(by + ty + i) * C + (bx + tx)];
  __syncthreads();
  for (int i = 0; i < 32; i += 8)
    out[(size_t)(bx + ty + i) * R + (by + tx)] = f2bf(tile[tx][ty + i]);
}

// ---------------- bf16 GEMM (m97-style): C[M,N] = A[M,K] * BT[N,K]^T (+bias) ----------------
__global__ __launch_bounds__(256) void gemm_bf16(
    const ushort* __restrict__ A, const ushort* __restrict__ BT,
    float* __restrict__ C, const float* __restrict__ bias,
    int M, int N, int K) {
  __shared__ alignas(16) ushort As[2][4096];
  __shared__ alignas(16) ushort Bs[2][4096];
  int tid = threadIdx.x;
  int wave = tid >> 6, lane = tid & 63;
  int l16 = lane & 15, lhi = lane >> 4;
  int m0 = blockIdx.y * 128, n0 = blockIdx.x * 128;
  int wr = (wave >> 1) * 64, wc = (wave & 1) * 64;
  int srow = lane >> 2, sch = lane & 3;

  f32x4 acc[4][4] = {};

  auto stage = [&](int kk, int buf) {
    for (int i = 0; i < 2; ++i) {
      int rg = i * 4 + wave;
      g2l16(A + (size_t)(m0 + rg * 16 + srow) * K + kk + sch * 8, &As[buf][rg * 512]);
      g2l16(BT + (size_t)(n0 + rg * 16 + srow) * K + kk + sch * 8, &Bs[buf][rg * 512]);
    }
  };

  stage(0, 0);
  int buf = 0;
  for (int kk = 0; kk < K; kk += 32) {
    __syncthreads();
    if (kk + 32 < K) stage(kk + 32, buf ^ 1);
    const ushort* Asb = As[buf];
    const ushort* Bsb = Bs[buf];
    bf16x8 af[4], bfr[4];
    for (int f = 0; f < 4; ++f)
      af[f] = *(const bf16x8*)(Asb + (wr + f * 16 + l16) * 32 + lhi * 8);
    for (int f = 0; f < 4; ++f)
      bfr[f] = *(const bf16x8*)(Bsb + (wc + f * 16 + l16) * 32 + lhi * 8);
    for (int fm = 0; fm < 4; ++fm)
      for (int fn = 0; fn < 4; ++fn)
        acc[fm][fn] = __builtin_amdgcn_mfma_f32_16x16x32_bf16(af[fm], bfr[fn], acc[fm][fn], 0, 0, 0);
    buf ^= 1;
  }
  for (int fm = 0; fm < 4; ++fm)
    for (int fn = 0; fn < 4; ++fn)
      for (int r = 0; r < 4; ++r) {
        int row = m0 + wr + fm * 16 + lhi * 4 + r;
        int col = n0 + wc + fn * 16 + l16;
        float v = acc[fm][fn][r];
        if (bias) v += bias[col];
        C[(size_t)row * N + col] = v;
      }
}

// ---------------- build Qaug/Kaug/V from qkv ----------------
__global__ __launch_bounds__(256) void augment_kernel(
    const float* __restrict__ qkv,  // [B*T, 3072]
    ushort* __restrict__ Qaug, ushort* __restrict__ Kaug, ushort* __restrict__ Vb) {
  int row = blockIdx.x;
  int b = row >> 11;
  int t = row & 2047;
  int tid = threadIdx.x;
  const float* src = qkv + (size_t)row * 3072;
  for (int i = 0; i < 4; ++i) {
    int idx = tid + i * 256;
    int h = idx >> 6, d = idx & 63;
    size_t obase = ((size_t)(b * H_ + h) * T_ + t);
    float q = src[idx];
    float k = src[1024 + idx];
    float v = src[2048 + idx];
    Qaug[obase * 128 + d] = f2bf(q * 0.125f);
    Kaug[obase * 128 + d] = f2bf(k);
    Vb[obase * 64 + d] = f2bf(v);
  }
  for (int i = 0; i < 2; ++i) {
    int idx = tid + i * 256;
    int h = idx >> 5, mm = idx & 31;
    int gdim = h * 64 + 2 * mm;
    float w = __expf(-9.2103403719761836f * (float)gdim * (1.0f / 1024.0f));
    float ang = w * (float)t;
    float si, co;
    __sincosf(ang, &si, &co);
    float qs = src[h * 64 + 2 * mm], qc = src[h * 64 + 2 * mm + 1];
    size_t obase = ((size_t)(b * H_ + h) * T_ + t);
    Qaug[obase * 128 + 64 + 2 * mm]     = f2bf((qs * si + qc * co) * 0.125f);
    Qaug[obase * 128 + 64 + 2 * mm + 1] = f2bf((qc * si - qs * co) * 0.125f);
    Kaug[obase * 128 + 64 + 2 * mm]     = f2bf(co);
    Kaug[obase * 128 + 64 + 2 * mm + 1] = f2bf(si);
  }
}

// ---------------- transpose V: [BH, T, 64] -> [BH, 64, T] ----------------
__global__ __launch_bounds__(256) void transpose_v(const ushort* __restrict__ Vb,
                                                   ushort* __restrict__ Vt) {
  __shared__ ushort tile[64][72];
  int bh = blockIdx.y, t0 = blockIdx.x * 64;
  int tid = threadIdx.x;
  for (int i = 0; i < 2; ++i) {
    int e = tid + i * 256;
    int row = e >> 3, ch = e & 7;
    *(int4*)(&tile[row][ch * 8]) =
        *(const int4*)(Vb + ((size_t)bh * T_ + t0 + row) * 64 + ch * 8);
  }
  __syncthreads();
  for (int i = 0; i < 2; ++i) {
    int e = tid + i * 256;
    int d = e >> 3, ch = e & 7;
    union { int4 v; ushort u[8]; } pk;
    for (int u = 0; u < 8; ++u) pk.u[u] = tile[ch * 8 + u][d];
    *(int4*)(Vt + ((size_t)bh * 64 + d) * T_ + t0 + ch * 8) = pk.v;
  }
}

// row-within-32 for 32x32 MFMA C/D layout
__device__ __forceinline__ int rowf32(int reg, int hi) {
  return (reg & 3) + 8 * (reg >> 2) + 4 * hi;
}

// ---------------- denominator kernel: 32x32 MFMA, quadrant waves ----------------
__global__ __launch_bounds__(256, 4) void denom_kernel(
    const ushort* __restrict__ Qaug,  // [BH, T, 128]
    const ushort* __restrict__ Kaug,  // [BH, T, 128]
    float* __restrict__ invlb) {      // [BH, T]
  int flat = blockIdx.y * 32 + blockIdx.x;
  int wg = (flat & 7) * 128 + (flat >> 3);
  int bh = wg >> 5;
  int qt = 31 - (wg & 31);
  int tid = threadIdx.x;
  int wave = tid >> 6, lane = tid & 63;
  int l31 = lane & 31, hi = lane >> 5;
  int r = wave >> 1, d = wave & 1;  // q-row block, key half

  __shared__ alignas(16) ushort Ks[2][8192];  // [key 0..63][128], chunk^(key&15)
  __shared__ float sums[64];

  const ushort* Kbase = Kaug + (size_t)bh * T_ * 128;

  auto stageK = [&](int kt, int buf) {
    for (int i = 0; i < 4; ++i) {
      int rg = i * 4 + wave;
      int key = rg * 4 + (lane >> 4);
      const ushort* g = Kbase + ((size_t)(kt * 64 + key)) * 128 + (((lane & 15) ^ (key & 15)) << 3);
      g2l16(g, &Ks[buf][rg * 512]);
    }
  };

  // Q -> registers: row = r*32 + l31, k = kstep*16 + hi*8 + j
  bf16x8 qf[8];
  {
    const ushort* Qg = Qaug + ((size_t)bh * T_ + qt * 64 + r * 32 + l31) * 128;
    for (int ks = 0; ks < 8; ++ks)
      qf[ks] = *(const bf16x8*)(Qg + ks * 16 + hi * 8);
  }
  int key = d * 32 + l31;

  stageK(0, 0);
  asm volatile("s_waitcnt vmcnt(0)" ::: "memory");
  __builtin_amdgcn_s_barrier();
  float plsum[16];
  for (int i = 0; i < 16; ++i) plsum[i] = 0.f;

  for (int kt = 0; kt <= qt; ++kt) {
    int buf = kt & 1;
    if (kt < qt) stageK(kt + 1, buf ^ 1);
    __builtin_amdgcn_sched_barrier(0);
    const ushort* Kb = Ks[buf];
    f32x16 s = {};
    for (int ks = 0; ks < 8; ++ks) {
      int slot = (ks * 2 + hi) ^ (key & 15);
      bf16x8 kf = *(const bf16x8*)(Kb + key * 128 + (slot << 3));
      s = __builtin_amdgcn_mfma_f32_32x32x16_bf16(qf[ks], kf, s, 0, 0, 0);
    }
    if (kt == qt) {
      for (int reg = 0; reg < 16; ++reg)
        if (d * 32 + l31 > r * 32 + rowf32(reg, hi)) s[reg] = -1e30f;
    }
    for (int reg = 0; reg < 16; ++reg) plsum[reg] += __expf(s[reg]);
    if (kt < qt) {
      asm volatile("s_waitcnt vmcnt(0)" ::: "memory");
      __builtin_amdgcn_s_barrier();
    }
  }
  // reduce over keys (l31) within wave
  for (int reg = 0; reg < 16; ++reg) {
    float v = plsum[reg];
    for (int dd = 1; dd < 32; dd <<= 1) v += __shfl_xor(v, dd);
    plsum[reg] = v;
  }
  // combine key-halves via LDS
  if (d == 1 && l31 == 0)
    for (int reg = 0; reg < 16; ++reg)
      sums[r * 32 + rowf32(reg, hi)] = plsum[reg];
  __syncthreads();
  if (d == 0 && l31 == 0)
    for (int reg = 0; reg < 16; ++reg) {
      int row = r * 32 + rowf32(reg, hi);
      invlb[(size_t)bh * T_ + qt * 64 + row] = 1.f / (plsum[reg] + sums[row]);
    }
}

// ---------------- attention main: 32x32 MFMA, quadrant waves ----------------
__global__ __launch_bounds__(256) void attn2_kernel(
    const ushort* __restrict__ Qaug,  // [BH, T, 128]
    const ushort* __restrict__ Kaug,  // [BH, T, 128]
    const ushort* __restrict__ Vt,    // [BH, 64, T]
    const float* __restrict__ invlb,  // [BH, T]
    float* __restrict__ score,        // [BH, T, T]
    ushort* __restrict__ ctxb) {      // [B*T, 1024] bf16
  int flat = blockIdx.y * 32 + blockIdx.x;
  int wg = (flat & 7) * 128 + (flat >> 3);
  int bh = wg >> 5;
  int qt = 31 - (wg & 31);
  int tid = threadIdx.x;
  int wave = tid >> 6, lane = tid & 63;
  int l31 = lane & 31, hi = lane >> 5;
  int r = wave >> 1, d = wave & 1;  // q-row block, key half

  __shared__ alignas(16) ushort Ks[2][8192];  // [key][128], chunk^(key&15)  (32 KB)
  __shared__ alignas(16) ushort Vs[2][4096];  // [dim][64 keys], chunk^(dim&7) (16 KB)
  __shared__ alignas(16) ushort Ps[4096];     // [qrow][64 keys], chunk^(row&7) (8 KB)

  const ushort* Kbase = Kaug + (size_t)bh * T_ * 128;
  const ushort* Vbase = Vt + (size_t)bh * 64 * T_;

  auto stageK = [&](int kt, int buf) {
    for (int i = 0; i < 4; ++i) {
      int rg = i * 4 + wave;
      int key = rg * 4 + (lane >> 4);
      const ushort* g = Kbase + ((size_t)(kt * 64 + key)) * 128 + (((lane & 15) ^ (key & 15)) << 3);
      g2l16(g, &Ks[buf][rg * 512]);
    }
  };
  auto stageV = [&](int kt, int buf) {
    for (int i = 0; i < 2; ++i) {
      int rg = i * 4 + wave;
      int dim = rg * 8 + (lane >> 3);
      const ushort* g = Vbase + (size_t)dim * T_ + kt * 64 + (((lane & 7) ^ (dim & 7)) << 3);
      g2l16(g, &Vs[buf][rg * 512]);
    }
  };

  // Q -> registers
  bf16x8 qf[8];
  {
    const ushort* Qg = Qaug + ((size_t)bh * T_ + qt * 64 + r * 32 + l31) * 128;
    for (int ks = 0; ks < 8; ++ks)
      qf[ks] = *(const bf16x8*)(Qg + ks * 16 + hi * 8);
  }
  int key = d * 32 + l31;
  // invl for this lane's 16 rows
  float4 iv[4];
  for (int g = 0; g < 4; ++g)
    iv[g] = *(const float4*)(invlb + (size_t)bh * T_ + qt * 64 + r * 32 + hi * 4 + g * 8);

  stageK(0, 0);
  stageV(0, 0);
  asm volatile("s_waitcnt vmcnt(0)" ::: "memory");
  __builtin_amdgcn_s_barrier();
  f32x16 cacc[2] = {};
  float* srow = score + ((size_t)bh * T_ + (size_t)qt * 64) * T_;

  for (int kt = 0; kt <= qt; ++kt) {
    int buf = kt & 1;
    if (kt < qt) { stageK(kt + 1, buf ^ 1); stageV(kt + 1, buf ^ 1); }
    __builtin_amdgcn_sched_barrier(0);
    // QK^T (wave quadrant: 32 q-rows x 32 keys)
    const ushort* Kb = Ks[buf];
    f32x16 s = {};
    for (int ks = 0; ks < 8; ++ks) {
      int slot = (ks * 2 + hi) ^ (key & 15);
      bf16x8 kf = *(const bf16x8*)(Kb + key * 128 + (slot << 3));
      s = __builtin_amdgcn_mfma_f32_32x32x16_bf16(qf[ks], kf, s, 0, 0, 0);
    }
    if (kt == qt) {
      for (int reg = 0; reg < 16; ++reg)
        if (d * 32 + l31 > r * 32 + rowf32(reg, hi)) s[reg] = -1e30f;
    }
    // softmax scale, score store (line-coalesced), Ps write
    for (int reg = 0; reg < 16; ++reg) {
      int row_loc = r * 32 + rowf32(reg, hi);
      float p = __expf(s[reg]) * iv[reg >> 2][reg & 3];
      srow[(size_t)row_loc * T_ + kt * 64 + key] = p;
      Ps[row_loc * 64 + ((((key >> 3)) ^ (row_loc & 7)) << 3) + (key & 7)] = f2bf(p);
    }
    // Ps is wave-private (rows r*32..r*32+31, keys d-half): wave-local wait
    asm volatile("s_waitcnt lgkmcnt(0)" ::: "memory");
    __builtin_amdgcn_sched_barrier(0);
    // PV over this wave's key half
    const ushort* Vb2 = Vs[buf];
    int rowA = r * 32 + l31;
    for (int ks2 = 0; ks2 < 2; ++ks2) {
      int chunkA = d * 4 + ks2 * 2 + hi;
      bf16x8 pa = *(const bf16x8*)(Ps + rowA * 64 + ((chunkA ^ (rowA & 7)) << 3));
      for (int b2 = 0; b2 < 2; ++b2) {
        int dim = b2 * 32 + l31;
        bf16x8 vb = *(const bf16x8*)(Vb2 + dim * 64 + ((chunkA ^ (dim & 7)) << 3));
        cacc[b2] = __builtin_amdgcn_mfma_f32_32x32x16_bf16(pa, vb, cacc[b2], 0, 0, 0);
      }
    }
    if (kt < qt) {
      // drain 6 staging loads; leave 16 score stores in flight
      asm volatile("s_waitcnt vmcnt(16)" ::: "memory");
      __builtin_amdgcn_s_barrier();
    }
  }

  // zero-fill upper-triangle tiles of score
  {
    int row = tid >> 2, c16 = (tid & 3) * 16;
    f32x4 z = {0.f, 0.f, 0.f, 0.f};
    for (int kt = qt + 1; kt < 32; ++kt) {
      f32x4* dst = (f32x4*)(srow + (size_t)row * T_ + kt * 64 + c16);
      for (int u = 0; u < 4; ++u) dst[u] = z;
    }
  }

  // combine key-half partial ctx across wave pairs, write ctxb
  __builtin_amdgcn_s_barrier();
  float* xch = (float*)Ks;  // 16 KB scratch (done with Ks)
  if (d == 1) {
    for (int b2 = 0; b2 < 2; ++b2)
      for (int reg = 0; reg < 16; ++reg)
        xch[(r * 32 + rowf32(reg, hi)) * 64 + b2 * 32 + l31] = cacc[b2][reg];
  }
  __syncthreads();
  if (d == 0) {
    int b = bh >> 4, h = bh & 15;
    for (int b2 = 0; b2 < 2; ++b2)
      for (int reg = 0; reg < 16; ++reg) {
        int row_loc = r * 32 + rowf32(reg, hi);
        float v = cacc[b2][reg] + xch[row_loc * 64 + b2 * 32 + l31];
        int t = qt * 64 + row_loc;
        ctxb[((size_t)(b * T_ + t)) * 1024 + h * 64 + b2 * 32 + l31] = f2bf(v);
      }
  }
}

extern "C" void kernel_launch(void* const* d_in, const int* in_sizes, int n_in,
                              void* d_out, int out_size, void* d_ws, size_t ws_size,
                              hipStream_t stream) {
  const float* x    = (const float*)d_in[0];
  const float* Wqkv = (const float*)d_in[2];
  const float* Wout = (const float*)d_in[3];
  const float* bout = (const float*)d_in[4];

  char* ws = (char*)d_ws;
  ushort* xb    = (ushort*)(ws + 0);           //  8 MB
  ushort* wqkvT = (ushort*)(ws + 8388608);     //  6 MB
  ushort* woutT = (ushort*)(ws + 14680064);    //  2 MB
  float*  qkv   = (float*) (ws + 16777216);    // 48 MB (dead after augment)
  ushort* Qaug  = (ushort*)(ws + 67108864);    // 16 MB
  ushort* Kaug  = (ushort*)(ws + 83886080);    // 16 MB
  ushort* Vb    = (ushort*)(ws + 100663296);   //  8 MB
  ushort* ctxb  = (ushort*)(ws + 109051904);   //  8 MB
  ushort* Vt    = (ushort*)(ws + 16777216);    //  8 MB, overlaps dead qkv
  float*  invlb = (float*) (ws + 25165824);    // 256 KB, after Vt in dead-qkv region

  float* out   = (float*)d_out;
  float* score = out + (size_t)4194304;  // B*T*D floats, then [B,H,T,T]

  cvt_kernel<<<4096, 256, 0, stream>>>(x, xb);
  dim3 tb(32, 8);
  transpose_cvt<<<dim3(3072 / 32, 1024 / 32), tb, 0, stream>>>(Wqkv, wqkvT, 1024, 3072);
  transpose_cvt<<<dim3(1024 / 32, 1024 / 32), tb, 0, stream>>>(Wout, woutT, 1024, 1024);
  gemm_bf16<<<dim3(24, 32), 256, 0, stream>>>(xb, wqkvT, qkv, nullptr, 4096, 3072, 1024);
  augment_kernel<<<4096, 256, 0, stream>>>(qkv, Qaug, Kaug, Vb);
  transpose_v<<<dim3(32, 32), 256, 0, stream>>>(Vb, Vt);
  denom_kernel<<<dim3(32, 32), 256, 0, stream>>>(Qaug, Kaug, invlb);
  attn2_kernel<<<dim3(32, 32), 256, 0, stream>>>(Qaug, Kaug, Vt, invlb, score, ctxb);
  gemm_bf16<<<dim3(8, 32), 256, 0, stream>>>(ctxb, woutT, out, bout, 4096, 1024, 1024);
}